// Round 20
// baseline (57.459 us; speedup 1.0000x reference)
//
#include <hip/hip_runtime.h>
#include <hip/hip_bf16.h>
#include <math.h>

#define H_IMG 128
#define W_IMG 128
#define N_G   1024
#define F_DIM 512
#define O_DIM 512
#define PIX   (H_IMG*W_IMG)        // 16384
#define FEAT_OFF 49152             // 3*PIX
#define RAD_OFF  (49152 + 512*16384)
#define MAXG  192                  // per-tile survivor cap (validated r2-r19)
#define WT_PITCH 200               // shorts; 400B row stride (16B-aligned)
#define GT_PITCH 72                // shorts; 144B row stride (16B-aligned)

typedef __attribute__((ext_vector_type(8))) short bf16x8;
typedef __attribute__((ext_vector_type(4))) float f32x4;

// ---------------------------------------------------------------------------
// Kernel 1: fused prep + rank + pack + cull-radius emit  [r16-exact]
// ---------------------------------------------------------------------------
__global__ __launch_bounds__(256) void preprank_kernel(
    const float* __restrict__ means,
    const float* __restrict__ opac,
    const float* __restrict__ colors,
    const float* __restrict__ scales,
    const float* __restrict__ rots,
    const float* __restrict__ view,
    const float* __restrict__ proj,
    int* __restrict__ order,
    float* __restrict__ psort,
    float* __restrict__ csort,
    float* __restrict__ rb,
    float* __restrict__ radii_out)
{
    __shared__ float d[N_G];
    __shared__ int pr[64][4];
    const int t = threadIdx.x;
    const float v2 = view[2], v6 = view[6], v10 = view[10], v14 = view[14];
    for (int i = t; i < N_G; i += 256)
        d[i] = means[3*i]*v2 + means[3*i+1]*v6 + means[3*i+2]*v10 + v14;
    __syncthreads();

    const int ln = t & 63;
    const int ch = t >> 6;
    const int n  = blockIdx.x*64 + ln;
    const float depth = d[n];

    {
        int rp = 0;
        const int mbeg = ch*256;
        for (int m = mbeg; m < mbeg + 256; ++m) {
            float dm = d[m];
            rp += (dm < depth) || (dm == depth && m < n);
        }
        pr[ln][ch] = rp;
    }
    __syncthreads();
    if (ch != 0) return;

    const int r = pr[ln][0] + pr[ln][1] + pr[ln][2] + pr[ln][3];

    float x = means[3*n], y = means[3*n+1], z = means[3*n+2];
    float pv0 = x*view[0] + y*view[4] + z*view[8]  + view[12];
    float pv1 = x*view[1] + y*view[5] + z*view[9]  + view[13];
    float ph0 = x*proj[0] + y*proj[4] + z*proj[8]  + proj[12];
    float ph1 = x*proj[1] + y*proj[5] + z*proj[9]  + proj[13];
    float phw = x*proj[3] + y*proj[7] + z*proj[11] + proj[15];
    float denom = phw + 1e-7f;
    float pp0 = ph0/denom, pp1 = ph1/denom;

    float qr=rots[4*n], qx=rots[4*n+1], qy=rots[4*n+2], qz=rots[4*n+3];
    float qn = sqrtf(qr*qr+qx*qx+qy*qy+qz*qz);
    qr/=qn; qx/=qn; qy/=qn; qz/=qn;
    float R00=1.f-2.f*(qy*qy+qz*qz), R01=2.f*(qx*qy-qr*qz), R02=2.f*(qx*qz+qr*qy);
    float R10=2.f*(qx*qy+qr*qz), R11=1.f-2.f*(qx*qx+qz*qz), R12=2.f*(qy*qz-qr*qx);
    float R20=2.f*(qx*qz-qr*qy), R21=2.f*(qy*qz+qr*qx), R22=1.f-2.f*(qx*qx+qy*qy);
    float s0=scales[3*n], s1=scales[3*n+1], s2=scales[3*n+2];
    float M00=R00*s0, M01=R01*s1, M02=R02*s2;
    float M10=R10*s0, M11=R11*s1, M12=R12*s2;
    float M20=R20*s0, M21=R21*s1, M22=R22*s2;
    float c00=M00*M00+M01*M01+M02*M02;
    float c01=M00*M10+M01*M11+M02*M12;
    float c02=M00*M20+M01*M21+M02*M22;
    float c11=M10*M10+M11*M11+M12*M12;
    float c12=M10*M20+M11*M21+M12*M22;
    float c22=M20*M20+M21*M21+M22*M22;

    const float fx=128.f, fy=128.f;
    float tz = depth;
    float txz = fminf(fmaxf(pv0/tz, -0.65f), 0.65f) * tz;
    float tyz = fminf(fmaxf(pv1/tz, -0.65f), 0.65f) * tz;
    float J00 = fx/tz,  J02 = -fx*txz/(tz*tz);
    float J11 = fy/tz,  J12 = -fy*tyz/(tz*tz);
    float T00=J00*view[0] + J02*view[2];
    float T01=J00*view[4] + J02*view[6];
    float T02=J00*view[8] + J02*view[10];
    float T10=J11*view[1] + J12*view[2];
    float T11=J11*view[5] + J12*view[6];
    float T12=J11*view[9] + J12*view[10];
    float u0 = T00*c00 + T01*c01 + T02*c02;
    float u1 = T00*c01 + T01*c11 + T02*c12;
    float u2 = T00*c02 + T01*c12 + T02*c22;
    float v0 = T10*c00 + T11*c01 + T12*c02;
    float v1 = T10*c01 + T11*c11 + T12*c12;
    float v2r= T10*c02 + T11*c12 + T12*c22;
    float a00 = u0*T00 + u1*T01 + u2*T02 + 0.3f;
    float a01 = u0*T10 + u1*T11 + u2*T12;
    float a11 = v0*T10 + v1*T11 + v2r*T12 + 0.3f;

    float det = a00*a11 - a01*a01;
    float dsafe = (det==0.f) ? 1.f : det;
    float inv = 1.f/dsafe;
    float con0 =  a11*inv, con1 = -a01*inv, con2 = a00*inv;
    float mid = 0.5f*(a00+a11);
    float lam1 = mid + sqrtf(fmaxf(0.1f, mid*mid - det));
    int irad = (int)ceilf(3.f*sqrtf(lam1));
    float pxc = ((pp0+1.f)*128.f - 1.f)*0.5f;
    float pyc = ((pp1+1.f)*128.f - 1.f)*0.5f;
    bool valid = (depth > 0.2f) && (det != 0.f);

    radii_out[n] = valid ? (float)irad : 0.f;
    order[r] = n;
    float* p = psort + 8*r;
    p[0]=pxc; p[1]=pyc; p[2]=con0; p[3]=con1; p[4]=con2;
    p[5]=opac[n]; p[6]=depth; p[7]= valid ? 1.f : 0.f;
    csort[4*r+0] = colors[3*n+0];
    csort[4*r+1] = colors[3*n+1];
    csort[4*r+2] = colors[3*n+2];
    csort[4*r+3] = 0.f;

    float op = opac[n];
    float tau = logf(255.f * op);
    bool active = valid && (tau > 0.f);
    float rx = active ? (sqrtf(2.f*tau*a00) + 0.01f) : -1.f;
    float ry = active ? (sqrtf(2.f*tau*a11) + 0.01f) : -1.f;
    rb[2*r+0] = rx;
    rb[2*r+1] = ry;
}

// ---------------------------------------------------------------------------
// Kernel 2: G[m][o] via MFMA, direct-from-global  [r16-exact]
// ---------------------------------------------------------------------------
__global__ __launch_bounds__(256) void gemmG_kernel(const float* __restrict__ S,
                                                    const float* __restrict__ Wm,
                                                    const int* __restrict__ order,
                                                    __hip_bfloat16* __restrict__ Gvb)
{
    const int t    = threadIdx.x;
    const int lane = t & 63;
    const int wv   = t >> 6;
    const int m0   = blockIdx.y * 64 + wv * 16;
    const int o0   = blockIdx.x * 16;
    const int lhi  = lane >> 4;
    const int llo  = lane & 15;

    const int arow = order[m0 + llo] & (N_G - 1);
    const float* Ar = S  + (size_t)arow*F_DIM + 8*lhi;
    const float* Br = Wm + (size_t)(o0 + llo)*F_DIM + 8*lhi;

    f32x4 acc = (f32x4){0.f,0.f,0.f,0.f};

    float4 a0 = *reinterpret_cast<const float4*>(Ar);
    float4 a1 = *reinterpret_cast<const float4*>(Ar + 4);
    float4 b0 = *reinterpret_cast<const float4*>(Br);
    float4 b1 = *reinterpret_cast<const float4*>(Br + 4);

    for (int k0 = 0; k0 < F_DIM; k0 += 32) {
        float4 na0, na1, nb0, nb1;
        const bool more = (k0 + 32) < F_DIM;
        if (more) {
            na0 = *reinterpret_cast<const float4*>(Ar + k0 + 32);
            na1 = *reinterpret_cast<const float4*>(Ar + k0 + 36);
            nb0 = *reinterpret_cast<const float4*>(Br + k0 + 32);
            nb1 = *reinterpret_cast<const float4*>(Br + k0 + 36);
        }
        bf16x8 af, bf;
        af[0]=__bfloat16_as_short(__float2bfloat16(a0.x));
        af[1]=__bfloat16_as_short(__float2bfloat16(a0.y));
        af[2]=__bfloat16_as_short(__float2bfloat16(a0.z));
        af[3]=__bfloat16_as_short(__float2bfloat16(a0.w));
        af[4]=__bfloat16_as_short(__float2bfloat16(a1.x));
        af[5]=__bfloat16_as_short(__float2bfloat16(a1.y));
        af[6]=__bfloat16_as_short(__float2bfloat16(a1.z));
        af[7]=__bfloat16_as_short(__float2bfloat16(a1.w));
        bf[0]=__bfloat16_as_short(__float2bfloat16(b0.x));
        bf[1]=__bfloat16_as_short(__float2bfloat16(b0.y));
        bf[2]=__bfloat16_as_short(__float2bfloat16(b0.z));
        bf[3]=__bfloat16_as_short(__float2bfloat16(b0.w));
        bf[4]=__bfloat16_as_short(__float2bfloat16(b1.x));
        bf[5]=__bfloat16_as_short(__float2bfloat16(b1.y));
        bf[6]=__bfloat16_as_short(__float2bfloat16(b1.z));
        bf[7]=__bfloat16_as_short(__float2bfloat16(b1.w));
        acc = __builtin_amdgcn_mfma_f32_16x16x32_bf16(af, bf, acc, 0, 0, 0);
        if (more) { a0 = na0; a1 = na1; b0 = nb0; b1 = nb1; }
    }

    #pragma unroll
    for (int r = 0; r < 4; ++r) {
        int row = m0 + 4*lhi + r;
        Gvb[(size_t)row*O_DIM + o0 + llo] = __float2bfloat16(acc[r]);
    }
}

// ---------------------------------------------------------------------------
// Kernel 3: fused alpha + featgemm  [r19 math; LDS trimmed for 2 blocks/CU]
//  - rb and csort read from global (L2) instead of LDS copies
//  - colbuf [16][64][3]
//  - featgemm phase runs 2 o-halves with GT[256][72]
//  LDS: uni=max(pg32K+colbuf12K+Pl4K, GT36.9K)=48K + WT25.6K + misc ~= 76KB
// ---------------------------------------------------------------------------
__global__ __launch_bounds__(1024) void alphafeat_kernel(
    const float* __restrict__ psort, const float* __restrict__ csort,
    const float* __restrict__ rb, const float* __restrict__ bg,
    const __hip_bfloat16* __restrict__ Gvb, const float* __restrict__ conv_b,
    float* __restrict__ out)
{
    __shared__ __align__(16) char uni[49152];
    float (*pg)[8]        = (float(*)[8])uni;                 // [0,32768)
    float (*colbuf)[64][3]= (float(*)[64][3])(uni + 32768);   // [32768,45056)
    float (*Pl)[64]       = (float(*)[64])(uni + 45056);      // [45056,49152)
    short (*GT)[GT_PITCH] = (short(*)[GT_PITCH])uni;          // 256*72*2=36864

    __shared__ short WT[64][WT_PITCH];                        // 25.6 KB
    __shared__ float Tfl[64];
    __shared__ int   idx_lds[MAXG];
    __shared__ int   cntl_s[16];
    __shared__ int   cnt_tot;

    const int t    = threadIdx.x;
    const int c    = t >> 6;        // wave = chunk
    const int lane = t & 63;
    const int tile = blockIdx.x;
    const int hrow = tile >> 1;
    const int w0   = (tile & 1) * 64;

    {
        float4* pgv = reinterpret_cast<float4*>(&pg[0][0]);
        const float4* ps4 = reinterpret_cast<const float4*>(psort);
        pgv[t]        = ps4[t];
        pgv[t + 1024] = ps4[t + 1024];
        int* wtz = (int*)&WT[0][0];
        for (int i = t; i < 64*WT_PITCH/2; i += 1024) wtz[i] = 0;
        if (t < MAXG) idx_lds[t] = 0;
    }
    __syncthreads();

    const float gx = (float)(w0 + lane);
    const float gy = (float)hrow;
    const float wlo = (float)w0;
    const float whi = (float)(w0 + 63);

    // ---- parallel gate eval: lane j tests gaussian c*64+j (rb via L2) ----
    unsigned long long hitmask;
    {
        int g = c*64 + lane;
        float2 R = reinterpret_cast<const float2*>(rb)[g];
        float2 Axy = *reinterpret_cast<const float2*>(&pg[g][0]);
        bool hit = (R.x >= 0.f) && (fabsf(Axy.y - gy) <= R.y)
                && (Axy.x >= wlo - R.x) && (Axy.x <= whi + R.x);
        hitmask = __ballot(hit);
    }

    // ---- pass 1: transmittance + survivor count over hit bits only ----
    float pref = 1.f;
    int cnt = 0;
    {
        unsigned long long m = hitmask;
        while (m) {
            int j = (int)__builtin_ctzll(m); m &= m - 1;
            int g = c*64 + j;
            float4 A = *reinterpret_cast<const float4*>(&pg[g][0]);
            float4 B = *reinterpret_cast<const float4*>(&pg[g][4]);
            float dx = A.x - gx, dy = A.y - gy;
            float pw = -0.5f*(A.z*dx*dx + B.x*dy*dy) - A.w*dx*dy;
            float al = fminf(0.99f, B.y*__expf(pw));
            bool keep = (pw <= 0.f) && (al >= (1.f/255.f)) && (B.w > 0.5f);
            float a = keep ? al : 0.f;
            float w = pref * a;
            pref *= 1.f - a;
            cnt += (__ballot(w > 1e-12f) != 0ull) ? 1 : 0;
        }
    }
    Pl[c][lane] = pref;
    if (lane == 0) cntl_s[c] = cnt;
    __syncthreads();

    int base = 0;
    float cp = 1.f;
    for (int cc = 0; cc < c; ++cc) {
        base += cntl_s[cc];
        cp *= Pl[cc][lane];
    }
    if (c == 15) {
        Tfl[lane] = cp * Pl[15][lane];
        if (lane == 0) {
            int tot = base + cntl_s[15];
            cnt_tot = (tot < MAXG) ? tot : MAXG;
        }
    }

    // ---- pass 2: weights -> WT LDS, color accum (csort via L2) ----
    float pref2 = 1.f;
    int slot = base;
    float col0 = 0.f, col1 = 0.f, col2 = 0.f;
    {
        unsigned long long m = hitmask;
        while (m) {
            int j = (int)__builtin_ctzll(m); m &= m - 1;
            int g = c*64 + j;
            float4 A = *reinterpret_cast<const float4*>(&pg[g][0]);
            float4 B = *reinterpret_cast<const float4*>(&pg[g][4]);
            float dx = A.x - gx, dy = A.y - gy;
            float pw = -0.5f*(A.z*dx*dx + B.x*dy*dy) - A.w*dx*dy;
            float al = fminf(0.99f, B.y*__expf(pw));
            bool keep = (pw <= 0.f) && (al >= (1.f/255.f)) && (B.w > 0.5f);
            float a = keep ? al : 0.f;
            float w = pref2 * a;
            pref2 *= 1.f - a;
            if (__ballot(w > 1e-12f) != 0ull) {
                float wfin = w * cp;
                if (slot < MAXG) {
                    WT[lane][slot] = __bfloat16_as_short(__float2bfloat16(wfin));
                    if (lane == 0) idx_lds[slot] = g;
                }
                float4 cv = *reinterpret_cast<const float4*>(&csort[4*g]);
                col0 += wfin*cv.x; col1 += wfin*cv.y; col2 += wfin*cv.z;
                ++slot;
            }
        }
    }

    colbuf[c][lane][0] = col0; colbuf[c][lane][1] = col1; colbuf[c][lane][2] = col2;
    __syncthreads();

    if (t < 64) {
        float r = 0.f, g = 0.f, b = 0.f;
        #pragma unroll
        for (int k = 0; k < 16; ++k) {
            r += colbuf[k][t][0]; g += colbuf[k][t][1]; b += colbuf[k][t][2];
        }
        float Tf = Tfl[t];
        int pix = hrow*W_IMG + w0 + t;
        out[0*PIX + pix] = r + Tf*bg[0];
        out[1*PIX + pix] = g + Tf*bg[1];
        out[2*PIX + pix] = b + Tf*bg[2];
    }
    __syncthreads();    // pg/colbuf/Pl dead; WT/idx/cnt_tot visible

    // ---- featgemm phase: 2 o-halves, 16 waves x 16 o each ----
    int scnt = cnt_tot;
    scnt = (scnt < 0) ? 0 : ((scnt > MAXG) ? MAXG : scnt);
    const short* gvs = (const short*)Gvb;
    const int nchunk = (scnt + 63) >> 6;
    const int pixbase = hrow*W_IMG + w0;

    for (int h = 0; h < 2; ++h) {
        const int ob = h * 256;
        f32x4 acc[4];
        #pragma unroll
        for (int j = 0; j < 4; ++j) acc[j] = (f32x4){0.f,0.f,0.f,0.f};

        for (int cc = 0; cc < nchunk; ++cc) {
            const int kbase = cc*64;
            {
                const int ol = t & 255;        // local o
                const int kg = t >> 8;         // 0..3 -> 16 k each
                #pragma unroll
                for (int b = 0; b < 2; ++b) {
                    bf16x8 s;
                    #pragma unroll
                    for (int j = 0; j < 8; ++j) {
                        int k = kbase + kg*16 + b*8 + j;
                        s[j] = (k < scnt) ? gvs[(size_t)idx_lds[k]*O_DIM + ob + ol] : (short)0;
                    }
                    *(bf16x8*)&GT[ol][kg*16 + b*8] = s;
                }
            }
            __syncthreads();

            #pragma unroll
            for (int ks = 0; ks < 2; ++ks) {
                const int kf = 8*(lane>>4);
                bf16x8 bfr[4];
                #pragma unroll
                for (int pt = 0; pt < 4; ++pt)
                    bfr[pt] = *(const bf16x8*)&WT[pt*16 + (lane&15)][kbase + ks*32 + kf];
                bf16x8 af = *(const bf16x8*)&GT[c*16 + (lane&15)][ks*32 + kf];
                #pragma unroll
                for (int pt = 0; pt < 4; ++pt)
                    acc[pt] = __builtin_amdgcn_mfma_f32_16x16x32_bf16(
                        af, bfr[pt], acc[pt], 0, 0, 0);
            }
            __syncthreads();
        }

        #pragma unroll
        for (int r = 0; r < 4; ++r) {
            int o = ob + c*16 + 4*(lane>>4) + r;
            float cb = conv_b[o];
            #pragma unroll
            for (int pt = 0; pt < 4; ++pt) {
                out[FEAT_OFF + (size_t)o*PIX + pixbase + pt*16 + (lane&15)]
                    = acc[pt][r] + cb;
            }
        }
    }
}

// ---------------------------------------------------------------------------
extern "C" void kernel_launch(void* const* d_in, const int* in_sizes, int n_in,
                              void* d_out, int out_size, void* d_ws, size_t ws_size,
                              hipStream_t stream)
{
    const float* means  = (const float*)d_in[0];
    const float* opac   = (const float*)d_in[2];
    const float* colors = (const float*)d_in[3];
    const float* sem    = (const float*)d_in[4];
    const float* scales = (const float*)d_in[5];
    const float* rots   = (const float*)d_in[6];
    const float* view   = (const float*)d_in[7];
    const float* proj   = (const float*)d_in[8];
    const float* bg     = (const float*)d_in[9];
    const float* conv_w = (const float*)d_in[11];
    const float* conv_b = (const float*)d_in[12];
    float* out = (float*)d_out;

    // --- workspace layout (f32 slots; sizes audited in BYTES) ---
    // psort: [0, 8192)        1024*8 f32
    // csort: [8192, 12288)    1024*4 f32
    // order: [12288, 13312)   1024 int
    // rb:    [13312, 15360)   1024*2 f32
    // Gvb:   [16384, 278528)  1024*512 bf16 = 1,048,576 B = 262,144 f32 slots
    float* wsf   = (float*)d_ws;
    float* psort = wsf;
    float* csort = wsf + 8192;
    int*   order = (int*)(wsf + 12288);
    float* rb    = wsf + 13312;
    __hip_bfloat16* Gvb = (__hip_bfloat16*)(wsf + 16384);

    float* radii_out = out + RAD_OFF;

    preprank_kernel<<<16, 256, 0, stream>>>(means, opac, colors, scales, rots,
                                            view, proj, order, psort, csort,
                                            rb, radii_out);
    gemmG_kernel<<<dim3(32,16), 256, 0, stream>>>(sem, conv_w, order, Gvb);
    alphafeat_kernel<<<256, 1024, 0, stream>>>(psort, csort, rb, bg, Gvb,
                                               conv_b, out);
}

// Round 21
// 43.848 us; speedup vs baseline: 1.3104x; 1.3104x over previous
//
#include <hip/hip_runtime.h>
#include <hip/hip_bf16.h>
#include <math.h>

#define H_IMG 128
#define W_IMG 128
#define N_G   1024
#define F_DIM 512
#define O_DIM 512
#define PIX   (H_IMG*W_IMG)        // 16384
#define FEAT_OFF 49152             // 3*PIX
#define RAD_OFF  (49152 + 512*16384)
#define MAXG  192                  // per-tile survivor cap (validated r2-r20)
#define WT_PITCH 200               // shorts; 400B row stride (16B-aligned)
#define GT_PITCH 72                // shorts; 144B row stride (16B-aligned)

typedef __attribute__((ext_vector_type(8))) short bf16x8;
typedef __attribute__((ext_vector_type(4))) float f32x4;

// ---------------------------------------------------------------------------
// Kernel 1: merged {prep+rank+pack+cull} (blocks 0..15) and gemmG (16..527).
// The two roles touch disjoint buffers; gemmG needs no sort order because
// Gvb rows are in ORIGINAL index order (alphafeat maps via psort[6] = id).
// ---------------------------------------------------------------------------
__global__ __launch_bounds__(256) void prep_gemm_kernel(
    const float* __restrict__ means,
    const float* __restrict__ opac,
    const float* __restrict__ colors,
    const float* __restrict__ scales,
    const float* __restrict__ rots,
    const float* __restrict__ view,
    const float* __restrict__ proj,
    const float* __restrict__ S,
    const float* __restrict__ Wm,
    float* __restrict__ psort,
    float* __restrict__ csort,
    float* __restrict__ rb,
    float* __restrict__ radii_out,
    __hip_bfloat16* __restrict__ Gvb)
{
    const int bid = blockIdx.x;
    if (bid >= 16) {
        // ------------------- gemmG role (512 blocks) ---------------------
        const int id   = bid - 16;
        const int t    = threadIdx.x;
        const int lane = t & 63;
        const int wv   = t >> 6;
        const int m0   = (id >> 5) * 64 + wv * 16;   // 16 m-tiles of 64
        const int o0   = (id & 31) * 16;             // 32 o-tiles of 16
        const int lhi  = lane >> 4;
        const int llo  = lane & 15;

        const int arow = m0 + llo;                   // identity (no gather)
        const float* Ar = S  + (size_t)arow*F_DIM + 8*lhi;
        const float* Br = Wm + (size_t)(o0 + llo)*F_DIM + 8*lhi;

        f32x4 acc = (f32x4){0.f,0.f,0.f,0.f};

        float4 a0 = *reinterpret_cast<const float4*>(Ar);
        float4 a1 = *reinterpret_cast<const float4*>(Ar + 4);
        float4 b0 = *reinterpret_cast<const float4*>(Br);
        float4 b1 = *reinterpret_cast<const float4*>(Br + 4);

        for (int k0 = 0; k0 < F_DIM; k0 += 32) {
            float4 na0, na1, nb0, nb1;
            const bool more = (k0 + 32) < F_DIM;
            if (more) {
                na0 = *reinterpret_cast<const float4*>(Ar + k0 + 32);
                na1 = *reinterpret_cast<const float4*>(Ar + k0 + 36);
                nb0 = *reinterpret_cast<const float4*>(Br + k0 + 32);
                nb1 = *reinterpret_cast<const float4*>(Br + k0 + 36);
            }
            bf16x8 af, bf;
            af[0]=__bfloat16_as_short(__float2bfloat16(a0.x));
            af[1]=__bfloat16_as_short(__float2bfloat16(a0.y));
            af[2]=__bfloat16_as_short(__float2bfloat16(a0.z));
            af[3]=__bfloat16_as_short(__float2bfloat16(a0.w));
            af[4]=__bfloat16_as_short(__float2bfloat16(a1.x));
            af[5]=__bfloat16_as_short(__float2bfloat16(a1.y));
            af[6]=__bfloat16_as_short(__float2bfloat16(a1.z));
            af[7]=__bfloat16_as_short(__float2bfloat16(a1.w));
            bf[0]=__bfloat16_as_short(__float2bfloat16(b0.x));
            bf[1]=__bfloat16_as_short(__float2bfloat16(b0.y));
            bf[2]=__bfloat16_as_short(__float2bfloat16(b0.z));
            bf[3]=__bfloat16_as_short(__float2bfloat16(b0.w));
            bf[4]=__bfloat16_as_short(__float2bfloat16(b1.x));
            bf[5]=__bfloat16_as_short(__float2bfloat16(b1.y));
            bf[6]=__bfloat16_as_short(__float2bfloat16(b1.z));
            bf[7]=__bfloat16_as_short(__float2bfloat16(b1.w));
            acc = __builtin_amdgcn_mfma_f32_16x16x32_bf16(af, bf, acc, 0, 0, 0);
            if (more) { a0 = na0; a1 = na1; b0 = nb0; b1 = nb1; }
        }

        #pragma unroll
        for (int r = 0; r < 4; ++r) {
            int row = m0 + 4*lhi + r;
            Gvb[(size_t)row*O_DIM + o0 + llo] = __float2bfloat16(acc[r]);
        }
        return;
    }

    // ---------------------- preprank role (16 blocks) ---------------------
    __shared__ float d[N_G];
    __shared__ int pr[64][4];
    const int t = threadIdx.x;
    const float v2 = view[2], v6 = view[6], v10 = view[10], v14 = view[14];
    for (int i = t; i < N_G; i += 256)
        d[i] = means[3*i]*v2 + means[3*i+1]*v6 + means[3*i+2]*v10 + v14;
    __syncthreads();

    const int ln = t & 63;
    const int ch = t >> 6;
    const int n  = bid*64 + ln;
    const float depth = d[n];

    {
        int rp = 0;
        const int mbeg = ch*256;
        for (int m = mbeg; m < mbeg + 256; ++m) {
            float dm = d[m];
            rp += (dm < depth) || (dm == depth && m < n);
        }
        pr[ln][ch] = rp;
    }
    __syncthreads();
    if (ch != 0) return;

    const int r = pr[ln][0] + pr[ln][1] + pr[ln][2] + pr[ln][3];

    float x = means[3*n], y = means[3*n+1], z = means[3*n+2];
    float pv0 = x*view[0] + y*view[4] + z*view[8]  + view[12];
    float pv1 = x*view[1] + y*view[5] + z*view[9]  + view[13];
    float ph0 = x*proj[0] + y*proj[4] + z*proj[8]  + proj[12];
    float ph1 = x*proj[1] + y*proj[5] + z*proj[9]  + proj[13];
    float phw = x*proj[3] + y*proj[7] + z*proj[11] + proj[15];
    float denom = phw + 1e-7f;
    float pp0 = ph0/denom, pp1 = ph1/denom;

    float qr=rots[4*n], qx=rots[4*n+1], qy=rots[4*n+2], qz=rots[4*n+3];
    float qn = sqrtf(qr*qr+qx*qx+qy*qy+qz*qz);
    qr/=qn; qx/=qn; qy/=qn; qz/=qn;
    float R00=1.f-2.f*(qy*qy+qz*qz), R01=2.f*(qx*qy-qr*qz), R02=2.f*(qx*qz+qr*qy);
    float R10=2.f*(qx*qy+qr*qz), R11=1.f-2.f*(qx*qx+qz*qz), R12=2.f*(qy*qz-qr*qx);
    float R20=2.f*(qx*qz-qr*qy), R21=2.f*(qy*qz+qr*qx), R22=1.f-2.f*(qx*qx+qy*qy);
    float s0=scales[3*n], s1=scales[3*n+1], s2=scales[3*n+2];
    float M00=R00*s0, M01=R01*s1, M02=R02*s2;
    float M10=R10*s0, M11=R11*s1, M12=R12*s2;
    float M20=R20*s0, M21=R21*s1, M22=R22*s2;
    float c00=M00*M00+M01*M01+M02*M02;
    float c01=M00*M10+M01*M11+M02*M12;
    float c02=M00*M20+M01*M21+M02*M22;
    float c11=M10*M10+M11*M11+M12*M12;
    float c12=M10*M20+M11*M21+M12*M22;
    float c22=M20*M20+M21*M21+M22*M22;

    const float fx=128.f, fy=128.f;
    float tz = depth;
    float txz = fminf(fmaxf(pv0/tz, -0.65f), 0.65f) * tz;
    float tyz = fminf(fmaxf(pv1/tz, -0.65f), 0.65f) * tz;
    float J00 = fx/tz,  J02 = -fx*txz/(tz*tz);
    float J11 = fy/tz,  J12 = -fy*tyz/(tz*tz);
    float T00=J00*view[0] + J02*view[2];
    float T01=J00*view[4] + J02*view[6];
    float T02=J00*view[8] + J02*view[10];
    float T10=J11*view[1] + J12*view[2];
    float T11=J11*view[5] + J12*view[6];
    float T12=J11*view[9] + J12*view[10];
    float u0 = T00*c00 + T01*c01 + T02*c02;
    float u1 = T00*c01 + T01*c11 + T02*c12;
    float u2 = T00*c02 + T01*c12 + T02*c22;
    float v0 = T10*c00 + T11*c01 + T12*c02;
    float v1 = T10*c01 + T11*c11 + T12*c12;
    float v2r= T10*c02 + T11*c12 + T12*c22;
    float a00 = u0*T00 + u1*T01 + u2*T02 + 0.3f;
    float a01 = u0*T10 + u1*T11 + u2*T12;
    float a11 = v0*T10 + v1*T11 + v2r*T12 + 0.3f;

    float det = a00*a11 - a01*a01;
    float dsafe = (det==0.f) ? 1.f : det;
    float inv = 1.f/dsafe;
    float con0 =  a11*inv, con1 = -a01*inv, con2 = a00*inv;
    float mid = 0.5f*(a00+a11);
    float lam1 = mid + sqrtf(fmaxf(0.1f, mid*mid - det));
    int irad = (int)ceilf(3.f*sqrtf(lam1));
    float pxc = ((pp0+1.f)*128.f - 1.f)*0.5f;
    float pyc = ((pp1+1.f)*128.f - 1.f)*0.5f;
    bool valid = (depth > 0.2f) && (det != 0.f);

    radii_out[n] = valid ? (float)irad : 0.f;
    float* p = psort + 8*r;
    p[0]=pxc; p[1]=pyc; p[2]=con0; p[3]=con1; p[4]=con2;
    p[5]=opac[n]; p[6]=(float)n; p[7]= valid ? 1.f : 0.f;   // [6] = original id
    csort[4*r+0] = colors[3*n+0];
    csort[4*r+1] = colors[3*n+1];
    csort[4*r+2] = colors[3*n+2];
    csort[4*r+3] = 0.f;

    float op = opac[n];
    float tau = logf(255.f * op);
    bool active = valid && (tau > 0.f);
    float rx = active ? (sqrtf(2.f*tau*a00) + 0.01f) : -1.f;
    float ry = active ? (sqrtf(2.f*tau*a11) + 0.01f) : -1.f;
    rb[2*r+0] = rx;
    rb[2*r+1] = ry;
}

// ---------------------------------------------------------------------------
// Kernel 2: fused alpha + featgemm  [r19-exact, except survivor id comes
// from psort[6] (original index) so Gvb can be unsorted]
// ---------------------------------------------------------------------------
__global__ __launch_bounds__(1024) void alphafeat_kernel(
    const float* __restrict__ psort, const float* __restrict__ csort,
    const float* __restrict__ rb, const float* __restrict__ bg,
    const __hip_bfloat16* __restrict__ Gvb, const float* __restrict__ conv_b,
    float* __restrict__ out)
{
    __shared__ __align__(16) char uni[73728];           // GT region (phase B)
    float (*pg)[8]       = (float(*)[8])uni;            // [0,32768)
    float (*cs)[4]       = (float(*)[4])(uni + 32768);  // [32768,49152)
    float (*colbuf)[64][4] = (float(*)[64][4])(uni + 49152); // [49152,65536)
    float (*Pl)[64]      = (float(*)[64])(uni + 65536); // [65536,69632)
    short (*GT)[GT_PITCH] = (short(*)[GT_PITCH])uni;    // 512*72*2 = 73728

    __shared__ short WT[64][WT_PITCH];                  // 25.6 KB
    __shared__ float rbl[N_G][2];                       // 8 KB
    __shared__ float Tfl[64];
    __shared__ int   idx_lds[MAXG];
    __shared__ int   cntl_s[16];
    __shared__ int   cnt_tot;

    const int t    = threadIdx.x;
    const int c    = t >> 6;        // wave = chunk
    const int lane = t & 63;
    const int tile = blockIdx.x;
    const int hrow = tile >> 1;
    const int w0   = (tile & 1) * 64;

    {
        float4* pgv = reinterpret_cast<float4*>(&pg[0][0]);
        const float4* ps4 = reinterpret_cast<const float4*>(psort);
        pgv[t]        = ps4[t];
        pgv[t + 1024] = ps4[t + 1024];
        float4* csv = reinterpret_cast<float4*>(&cs[0][0]);
        csv[t] = reinterpret_cast<const float4*>(csort)[t];
        reinterpret_cast<float2*>(&rbl[0][0])[t] =
            reinterpret_cast<const float2*>(rb)[t];
        int* wtz = (int*)&WT[0][0];
        for (int i = t; i < 64*WT_PITCH/2; i += 1024) wtz[i] = 0;
        if (t < MAXG) idx_lds[t] = 0;
    }
    __syncthreads();

    const float gx = (float)(w0 + lane);
    const float gy = (float)hrow;
    const float wlo = (float)w0;
    const float whi = (float)(w0 + 63);

    // ---- parallel gate eval: lane j tests gaussian c*64+j ----
    unsigned long long hitmask;
    {
        int g = c*64 + lane;
        float2 R = *reinterpret_cast<const float2*>(&rbl[g][0]);
        float2 Axy = *reinterpret_cast<const float2*>(&pg[g][0]);
        bool hit = (R.x >= 0.f) && (fabsf(Axy.y - gy) <= R.y)
                && (Axy.x >= wlo - R.x) && (Axy.x <= whi + R.x);
        hitmask = __ballot(hit);
    }

    // ---- pass 1: transmittance + survivor count over hit bits only ----
    float pref = 1.f;
    int cnt = 0;
    {
        unsigned long long m = hitmask;
        while (m) {
            int j = (int)__builtin_ctzll(m); m &= m - 1;
            int g = c*64 + j;
            float4 A = *reinterpret_cast<const float4*>(&pg[g][0]);
            float4 B = *reinterpret_cast<const float4*>(&pg[g][4]);
            float dx = A.x - gx, dy = A.y - gy;
            float pw = -0.5f*(A.z*dx*dx + B.x*dy*dy) - A.w*dx*dy;
            float al = fminf(0.99f, B.y*__expf(pw));
            bool keep = (pw <= 0.f) && (al >= (1.f/255.f)) && (B.w > 0.5f);
            float a = keep ? al : 0.f;
            float w = pref * a;
            pref *= 1.f - a;
            cnt += (__ballot(w > 1e-12f) != 0ull) ? 1 : 0;
        }
    }
    Pl[c][lane] = pref;
    if (lane == 0) cntl_s[c] = cnt;
    __syncthreads();

    int base = 0;
    float cp = 1.f;
    for (int cc = 0; cc < c; ++cc) {
        base += cntl_s[cc];
        cp *= Pl[cc][lane];
    }
    if (c == 15) {
        Tfl[lane] = cp * Pl[15][lane];
        if (lane == 0) {
            int tot = base + cntl_s[15];
            cnt_tot = (tot < MAXG) ? tot : MAXG;
        }
    }

    // ---- pass 2: weights -> WT LDS, color accum (hit bits only) ----
    float pref2 = 1.f;
    int slot = base;
    float col0 = 0.f, col1 = 0.f, col2 = 0.f;
    {
        unsigned long long m = hitmask;
        while (m) {
            int j = (int)__builtin_ctzll(m); m &= m - 1;
            int g = c*64 + j;
            float4 A = *reinterpret_cast<const float4*>(&pg[g][0]);
            float4 B = *reinterpret_cast<const float4*>(&pg[g][4]);
            float dx = A.x - gx, dy = A.y - gy;
            float pw = -0.5f*(A.z*dx*dx + B.x*dy*dy) - A.w*dx*dy;
            float al = fminf(0.99f, B.y*__expf(pw));
            bool keep = (pw <= 0.f) && (al >= (1.f/255.f)) && (B.w > 0.5f);
            float a = keep ? al : 0.f;
            float w = pref2 * a;
            pref2 *= 1.f - a;
            if (__ballot(w > 1e-12f) != 0ull) {
                float wfin = w * cp;
                if (slot < MAXG) {
                    WT[lane][slot] = __bfloat16_as_short(__float2bfloat16(wfin));
                    if (lane == 0) idx_lds[slot] = (int)B.z;   // original id
                }
                float4 cv = *reinterpret_cast<const float4*>(&cs[g][0]);
                col0 += wfin*cv.x; col1 += wfin*cv.y; col2 += wfin*cv.z;
                ++slot;
            }
        }
    }

    colbuf[c][lane][0] = col0; colbuf[c][lane][1] = col1; colbuf[c][lane][2] = col2;
    __syncthreads();

    if (t < 64) {
        float r = 0.f, g = 0.f, b = 0.f;
        #pragma unroll
        for (int k = 0; k < 16; ++k) {
            r += colbuf[k][t][0]; g += colbuf[k][t][1]; b += colbuf[k][t][2];
        }
        float Tf = Tfl[t];
        int pix = hrow*W_IMG + w0 + t;
        out[0*PIX + pix] = r + Tf*bg[0];
        out[1*PIX + pix] = g + Tf*bg[1];
        out[2*PIX + pix] = b + Tf*bg[2];
    }
    __syncthreads();    // colbuf/pg/cs dead; WT/idx/cnt_tot visible

    // ---- featgemm phase: 16 waves x 32 o  [r19-exact] ----
    int scnt = cnt_tot;
    scnt = (scnt < 0) ? 0 : ((scnt > MAXG) ? MAXG : scnt);
    const short* gvs = (const short*)Gvb;

    f32x4 acc[2][4];
    #pragma unroll
    for (int i = 0; i < 2; ++i)
        #pragma unroll
        for (int j = 0; j < 4; ++j)
            acc[i][j] = (f32x4){0.f,0.f,0.f,0.f};

    const int nchunk = (scnt + 63) >> 6;
    for (int cc = 0; cc < nchunk; ++cc) {
        const int kbase = cc*64;
        {
            const int o = t & 511;
            const int half = t >> 9;
            #pragma unroll
            for (int b = 0; b < 4; ++b) {
                bf16x8 s;
                #pragma unroll
                for (int j = 0; j < 8; ++j) {
                    int k = kbase + half*32 + b*8 + j;
                    s[j] = (k < scnt) ? gvs[(size_t)idx_lds[k]*O_DIM + o] : (short)0;
                }
                *(bf16x8*)&GT[o][half*32 + b*8] = s;
            }
        }
        __syncthreads();

        #pragma unroll
        for (int ks = 0; ks < 2; ++ks) {
            const int kf = 8*(lane>>4);
            bf16x8 bfr[4];
            #pragma unroll
            for (int pt = 0; pt < 4; ++pt)
                bfr[pt] = *(const bf16x8*)&WT[pt*16 + (lane&15)][kbase + ks*32 + kf];
            #pragma unroll
            for (int ot = 0; ot < 2; ++ot) {
                bf16x8 af = *(const bf16x8*)&GT[c*32 + ot*16 + (lane&15)][ks*32 + kf];
                #pragma unroll
                for (int pt = 0; pt < 4; ++pt)
                    acc[ot][pt] = __builtin_amdgcn_mfma_f32_16x16x32_bf16(
                        af, bfr[pt], acc[ot][pt], 0, 0, 0);
            }
        }
        __syncthreads();
    }

    const int pixbase = hrow*W_IMG + w0;
    #pragma unroll
    for (int ot = 0; ot < 2; ++ot) {
        #pragma unroll
        for (int r = 0; r < 4; ++r) {
            int o = c*32 + ot*16 + 4*(lane>>4) + r;
            float cb = conv_b[o];
            #pragma unroll
            for (int pt = 0; pt < 4; ++pt) {
                out[FEAT_OFF + (size_t)o*PIX + pixbase + pt*16 + (lane&15)]
                    = acc[ot][pt][r] + cb;
            }
        }
    }
}

// ---------------------------------------------------------------------------
extern "C" void kernel_launch(void* const* d_in, const int* in_sizes, int n_in,
                              void* d_out, int out_size, void* d_ws, size_t ws_size,
                              hipStream_t stream)
{
    const float* means  = (const float*)d_in[0];
    const float* opac   = (const float*)d_in[2];
    const float* colors = (const float*)d_in[3];
    const float* sem    = (const float*)d_in[4];
    const float* scales = (const float*)d_in[5];
    const float* rots   = (const float*)d_in[6];
    const float* view   = (const float*)d_in[7];
    const float* proj   = (const float*)d_in[8];
    const float* bg     = (const float*)d_in[9];
    const float* conv_w = (const float*)d_in[11];
    const float* conv_b = (const float*)d_in[12];
    float* out = (float*)d_out;

    // --- workspace layout (f32 slots; sizes audited in BYTES) ---
    // psort: [0, 8192)        1024*8 f32
    // csort: [8192, 12288)    1024*4 f32
    // rb:    [13312, 15360)   1024*2 f32
    // Gvb:   [16384, 278528)  1024*512 bf16 = 1,048,576 B = 262,144 f32 slots
    float* wsf   = (float*)d_ws;
    float* psort = wsf;
    float* csort = wsf + 8192;
    float* rb    = wsf + 13312;
    __hip_bfloat16* Gvb = (__hip_bfloat16*)(wsf + 16384);

    float* radii_out = out + RAD_OFF;

    prep_gemm_kernel<<<528, 256, 0, stream>>>(means, opac, colors, scales,
                                              rots, view, proj, sem, conv_w,
                                              psort, csort, rb, radii_out, Gvb);
    alphafeat_kernel<<<256, 1024, 0, stream>>>(psort, csort, rb, bg, Gvb,
                                               conv_b, out);
}